// Round 16
// baseline (357.489 us; speedup 1.0000x reference)
//
#include <hip/hip_runtime.h>

#define NN 16384
#define FIN 128
#define FH 64
#define FO 32

typedef __attribute__((ext_vector_type(8))) short bf16x8;
typedef __attribute__((ext_vector_type(4))) float f32x4;

__device__ inline unsigned short f2bf(float f) {          // round-to-nearest-even
    unsigned int u = __float_as_uint(f);
    unsigned int r = (u + 0x7FFFu + ((u >> 16) & 1u)) >> 16;
    return (unsigned short)r;
}
__device__ inline float bf2f(unsigned short b) {
    return __uint_as_float((unsigned int)b << 16);
}

// ---------------- CSR build ----------------

__global__ void k_zero(int* __restrict__ cnt) {
    int i = blockIdx.x * 256 + threadIdx.x;
    cnt[i] = 0;
}

__global__ void k_count(const int* __restrict__ dst, int* __restrict__ cnt, int E) {
    int e = blockIdx.x * 256 + threadIdx.x;
    if (e < E) atomicAdd(&cnt[dst[e] & (NN - 1)], 1);
}

// exclusive scan + dinv + cursor init, single block
__global__ __launch_bounds__(256) void k_scan(const int* __restrict__ cnt,
                                              int* __restrict__ row,
                                              float* __restrict__ dinv,
                                              int* __restrict__ cur) {
    __shared__ int part[256];
    __shared__ int off[257];
    int t = threadIdx.x;
    int base = t * 64;
    int s = 0;
    for (int i = 0; i < 64; ++i) s += cnt[base + i];
    part[t] = s;
    __syncthreads();
    if (t == 0) {
        int a = 0;
        for (int i = 0; i < 256; ++i) { off[i] = a; a += part[i]; }
        off[256] = a;
    }
    __syncthreads();
    int a = off[t];
    for (int i = 0; i < 64; ++i) {
        int c = cnt[base + i];
        row[base + i] = a; a += c;
        dinv[base + i] = rsqrtf((float)c + 1.0f);
        cur[base + i] = 0;
    }
    if (t == 0) row[NN] = off[256];
}

// fat kernel: blocks [0,nf) do CSR fill; blocks [nf, nf+NN/4) do h0 = x@W1
__global__ void k_fill_h0(const int* __restrict__ src, const int* __restrict__ dst,
                          const int* __restrict__ row, int* __restrict__ cur,
                          const float* __restrict__ dinv,
                          int* __restrict__ csr_s, float* __restrict__ csr_w, int E, int nf,
                          const float* __restrict__ x, const float* __restrict__ W1,
                          float* __restrict__ h0) {
    int b = blockIdx.x;
    if (b < nf) {
        int e = b * 256 + threadIdx.x;
        if (e >= E) return;
        int s = src[e] & (NN - 1), d = dst[e] & (NN - 1);
        int pos = atomicAdd(&cur[d], 1);
        int slot = row[d] + pos;
        csr_s[slot] = s;
        csr_w[slot] = dinv[s] * dinv[d];
    } else {
        int r = (b - nf) * 4 + (threadIdx.x >> 6);
        int col = threadIdx.x & 63;
        const float* xr = x + r * FIN;
        float acc = 0.f;
#pragma unroll 8
        for (int k = 0; k < FIN; ++k)
            acc = fmaf(xr[k], W1[k * FH + col], acc);
        h0[r * FH + col] = acc;
    }
}

// ---------------- fused layer-1 propagate + ReLU + layer-2 transform ----------
__global__ void k_prop1t(const int* __restrict__ row, const int* __restrict__ csr_s,
                         const float* __restrict__ csr_w, const float* __restrict__ dinv,
                         const float* __restrict__ h0, const float* __restrict__ b1,
                         const float* __restrict__ Wmu, const float* __restrict__ Wls,
                         float* __restrict__ tmu, float* __restrict__ tls) {
    int t = blockIdx.x * 256 + threadIdx.x;
    int i = t >> 6, l = t & 63;
    int beg = row[i], end = row[i + 1];
    float di = dinv[i];
    float acc = di * di * h0[i * FH + l];
    for (int j = beg; j < end; ++j) {
        int s = csr_s[j];
        float w = csr_w[j];
        acc = fmaf(w, h0[s * FH + l], acc);
    }
    float v = acc + b1[l];
    v = v > 0.f ? v : 0.f;           // h[i][l] in one VGPR/lane

    const float* W = (l < 32) ? Wmu : Wls;
    int c = l & 31;
    float o = 0.f;
#pragma unroll
    for (int k = 0; k < FH; ++k)
        o = fmaf(__shfl(v, k), W[k * FO + c], o);
    if (l < 32) tmu[i * FO + c] = o;
    else        tls[i * FO + c] = o;
}

// layer-2 propagate + reparameterize + bf16 hi/lo split of z
__global__ void k_prop2g(const int* __restrict__ row, const int* __restrict__ csr_s,
                         const float* __restrict__ csr_w, const float* __restrict__ dinv,
                         const float* __restrict__ tmu, const float* __restrict__ tls,
                         const float* __restrict__ bmu, const float* __restrict__ bls,
                         const float* __restrict__ eps,
                         float* __restrict__ mu_out, float* __restrict__ ls_out,
                         unsigned short* __restrict__ zh, unsigned short* __restrict__ zl) {
    int t = blockIdx.x * 256 + threadIdx.x;
    int i = t >> 6, l = t & 63;
    int c = l & 31;
    int beg = row[i], end = row[i + 1];
    const float* tp = (l < 32) ? tmu : tls;
    float di = dinv[i];
    float acc = di * di * tp[i * FO + c];
    for (int j = beg; j < end; ++j) {
        int s = csr_s[j];
        float w = csr_w[j];
        acc = fmaf(w, tp[s * FO + c], acc);
    }
    float v = acc + ((l < 32) ? bmu[c] : bls[c]);
    if (l < 32) mu_out[i * FO + c] = v;
    else        ls_out[i * FO + c] = v;
    float other = __shfl_xor(v, 32);   // lane<32 gets ls
    if (l < 32) {
        float zf = fmaf(eps[i * FO + c], __expf(other), v);
        unsigned short hb = f2bf(zf);
        zh[i * FO + c] = hb;
        zl[i * FO + c] = f2bf(zf - bf2f(hb));
    }
}

// ---------------- decode: adj = sigmoid(z @ z^T) ----------------
// PERSISTENT-BAND version: 1024 blocks (4 resident/CU), block bi owns the
// complete 16-row band (16 x 16384 = 1MB, written fully sequentially).
// Inner loop over 16 col-panels x 2 groups keeps every wave's store pipe
// continuously fed (fill-kernel structure); prologue ramp paid once per band
// instead of once per 64KB tile. Wave-private slab, no barriers, nt stores.
__global__ __launch_bounds__(256, 4) void k_decode(const unsigned short* __restrict__ zh,
                                                   const unsigned short* __restrict__ zl,
                                                   float* __restrict__ out) {
    __shared__ float slab[4][16][136];   // 34.8 KB -> 4 blocks/CU
    int bi = blockIdx.x;                 // one 16-row band per block
    int w = threadIdx.x >> 6;
    int l = threadIdx.x & 63;
    int lr = l & 15, lg = l >> 4;

    auto ld = [&](const unsigned short* p, int t) -> bf16x8 {
        return *(const bf16x8*)(p + ((size_t)t * 16 + lr) * FO + lg * 8);
    };

    bf16x8 rh = ld(zh, bi), rl = ld(zl, bi);   // rows bi*16..+15, loaded once

    for (int bj = 0; bj < 16; ++bj) {
        int ctbase = bj * 64 + w * 16;
#pragma unroll
        for (int g = 0; g < 2; ++g) {
            // compute 8 col-tiles (128 cols) into the slab
#pragma unroll
            for (int j = 0; j < 8; ++j) {
                int ct = ctbase + g * 8 + j;
                bf16x8 ch = ld(zh, ct);
                bf16x8 cl = ld(zl, ct);
                f32x4 a = {0.f, 0.f, 0.f, 0.f};
                a = __builtin_amdgcn_mfma_f32_16x16x32_bf16(ch, rh, a, 0, 0, 0);
                a = __builtin_amdgcn_mfma_f32_16x16x32_bf16(ch, rl, a, 0, 0, 0);
                a = __builtin_amdgcn_mfma_f32_16x16x32_bf16(cl, rh, a, 0, 0, 0);
                float4 v;
                v.x = __builtin_amdgcn_rcpf(1.f + __expf(-a[0]));
                v.y = __builtin_amdgcn_rcpf(1.f + __expf(-a[1]));
                v.z = __builtin_amdgcn_rcpf(1.f + __expf(-a[2]));
                v.w = __builtin_amdgcn_rcpf(1.f + __expf(-a[3]));
                *(float4*)&slab[w][lr][j * 16 + lg * 4] = v;
            }
            // write out: 8 insts, each = 2 rows x 512B contiguous, non-temporal
            size_t cbase = (size_t)bj * 1024 + w * 256 + g * 128;
#pragma unroll
            for (int inst = 0; inst < 8; ++inst) {
                int r = inst * 2 + (l >> 5);
                int f4 = l & 31;
                f32x4 v = *(const f32x4*)&slab[w][r][f4 * 4];
                f32x4* dst = (f32x4*)(out + ((size_t)(bi * 16 + r)) * NN + cbase + f4 * 4);
                __builtin_nontemporal_store(v, dst);
            }
        }
    }
}

// ---------------- launch ----------------

extern "C" void kernel_launch(void* const* d_in, const int* in_sizes, int n_in,
                              void* d_out, int out_size, void* d_ws, size_t ws_size,
                              hipStream_t stream) {
    const float* x    = (const float*)d_in[0];
    const int*   ei   = (const int*)d_in[1];
    const float* W1   = (const float*)d_in[2];
    const float* b1   = (const float*)d_in[3];
    const float* Wmu  = (const float*)d_in[4];
    const float* bmu  = (const float*)d_in[5];
    const float* Wls  = (const float*)d_in[6];
    const float* bls  = (const float*)d_in[7];
    const float* eps  = (const float*)d_in[8];

    int E = in_sizes[1] / 2;
    int nf = (E + 255) / 256;
    const int* src = ei;
    const int* dst = ei + E;

    float* ws = (float*)d_ws;
    float* dinv  = ws;                         // NN f32
    int*   cnt   = (int*)(dinv + NN);          // NN
    int*   row   = cnt + NN;                   // NN+16
    int*   cur   = row + NN + 16;              // NN
    int*   csr_s = cur + NN;                   // E
    float* csr_w = (float*)(csr_s + E);        // E
    float* h0    = csr_w + E;                  // NN*FH
    float* tmu   = h0 + (size_t)NN * FH;       // NN*FO
    float* tls   = tmu + (size_t)NN * FO;      // NN*FO
    unsigned short* zh = (unsigned short*)(tls + (size_t)NN * FO);  // NN*FO u16
    unsigned short* zl = zh + (size_t)NN * FO;                      // NN*FO u16

    float* adj    = (float*)d_out;
    float* mu_out = adj + (size_t)NN * NN;
    float* ls_out = mu_out + (size_t)NN * FO;

    k_zero<<<NN / 256, 256, 0, stream>>>(cnt);
    k_count<<<nf, 256, 0, stream>>>(dst, cnt, E);
    k_scan<<<1, 256, 0, stream>>>(cnt, row, dinv, cur);
    k_fill_h0<<<nf + NN / 4, 256, 0, stream>>>(src, dst, row, cur, dinv,
                                               csr_s, csr_w, E, nf, x, W1, h0);
    k_prop1t<<<NN * FH / 256, 256, 0, stream>>>(row, csr_s, csr_w, dinv, h0, b1,
                                                Wmu, Wls, tmu, tls);
    k_prop2g<<<NN * FH / 256, 256, 0, stream>>>(row, csr_s, csr_w, dinv, tmu, tls,
                                                bmu, bls, eps, mu_out, ls_out, zh, zl);
    k_decode<<<NN / 16, 256, 0, stream>>>(zh, zl, adj);
}

// Round 17
// 311.124 us; speedup vs baseline: 1.1490x; 1.1490x over previous
//
#include <hip/hip_runtime.h>

#define NN 16384
#define FIN 128
#define FH 64
#define FO 32

typedef __attribute__((ext_vector_type(8))) short bf16x8;
typedef __attribute__((ext_vector_type(4))) float f32x4;

__device__ inline unsigned short f2bf(float f) {          // round-to-nearest-even
    unsigned int u = __float_as_uint(f);
    unsigned int r = (u + 0x7FFFu + ((u >> 16) & 1u)) >> 16;
    return (unsigned short)r;
}
__device__ inline float bf2f(unsigned short b) {
    return __uint_as_float((unsigned int)b << 16);
}

// ---------------- CSR build ----------------

__global__ void k_zero(int* __restrict__ cnt) {
    int i = blockIdx.x * 256 + threadIdx.x;
    cnt[i] = 0;
}

__global__ void k_count(const int* __restrict__ dst, int* __restrict__ cnt, int E) {
    int e = blockIdx.x * 256 + threadIdx.x;
    if (e < E) atomicAdd(&cnt[dst[e] & (NN - 1)], 1);
}

// exclusive scan + dinv + cursor init, single block
__global__ __launch_bounds__(256) void k_scan(const int* __restrict__ cnt,
                                              int* __restrict__ row,
                                              float* __restrict__ dinv,
                                              int* __restrict__ cur) {
    __shared__ int part[256];
    __shared__ int off[257];
    int t = threadIdx.x;
    int base = t * 64;
    int s = 0;
    for (int i = 0; i < 64; ++i) s += cnt[base + i];
    part[t] = s;
    __syncthreads();
    if (t == 0) {
        int a = 0;
        for (int i = 0; i < 256; ++i) { off[i] = a; a += part[i]; }
        off[256] = a;
    }
    __syncthreads();
    int a = off[t];
    for (int i = 0; i < 64; ++i) {
        int c = cnt[base + i];
        row[base + i] = a; a += c;
        dinv[base + i] = rsqrtf((float)c + 1.0f);
        cur[base + i] = 0;
    }
    if (t == 0) row[NN] = off[256];
}

// fat kernel: blocks [0,nf) do CSR fill; blocks [nf, nf+NN/4) do h0 = x@W1
__global__ void k_fill_h0(const int* __restrict__ src, const int* __restrict__ dst,
                          const int* __restrict__ row, int* __restrict__ cur,
                          const float* __restrict__ dinv,
                          int* __restrict__ csr_s, float* __restrict__ csr_w, int E, int nf,
                          const float* __restrict__ x, const float* __restrict__ W1,
                          float* __restrict__ h0) {
    int b = blockIdx.x;
    if (b < nf) {
        int e = b * 256 + threadIdx.x;
        if (e >= E) return;
        int s = src[e] & (NN - 1), d = dst[e] & (NN - 1);
        int pos = atomicAdd(&cur[d], 1);
        int slot = row[d] + pos;
        csr_s[slot] = s;
        csr_w[slot] = dinv[s] * dinv[d];
    } else {
        int r = (b - nf) * 4 + (threadIdx.x >> 6);
        int col = threadIdx.x & 63;
        const float* xr = x + r * FIN;
        float acc = 0.f;
#pragma unroll 8
        for (int k = 0; k < FIN; ++k)
            acc = fmaf(xr[k], W1[k * FH + col], acc);
        h0[r * FH + col] = acc;
    }
}

// ---------------- fused layer-1 propagate + ReLU + layer-2 transform ----------
__global__ void k_prop1t(const int* __restrict__ row, const int* __restrict__ csr_s,
                         const float* __restrict__ csr_w, const float* __restrict__ dinv,
                         const float* __restrict__ h0, const float* __restrict__ b1,
                         const float* __restrict__ Wmu, const float* __restrict__ Wls,
                         float* __restrict__ tmu, float* __restrict__ tls) {
    int t = blockIdx.x * 256 + threadIdx.x;
    int i = t >> 6, l = t & 63;
    int beg = row[i], end = row[i + 1];
    float di = dinv[i];
    float acc = di * di * h0[i * FH + l];
    for (int j = beg; j < end; ++j) {
        int s = csr_s[j];
        float w = csr_w[j];
        acc = fmaf(w, h0[s * FH + l], acc);
    }
    float v = acc + b1[l];
    v = v > 0.f ? v : 0.f;           // h[i][l] in one VGPR/lane

    const float* W = (l < 32) ? Wmu : Wls;
    int c = l & 31;
    float o = 0.f;
#pragma unroll
    for (int k = 0; k < FH; ++k)
        o = fmaf(__shfl(v, k), W[k * FO + c], o);
    if (l < 32) tmu[i * FO + c] = o;
    else        tls[i * FO + c] = o;
}

// layer-2 propagate + reparameterize + bf16 hi/lo split of z
__global__ void k_prop2g(const int* __restrict__ row, const int* __restrict__ csr_s,
                         const float* __restrict__ csr_w, const float* __restrict__ dinv,
                         const float* __restrict__ tmu, const float* __restrict__ tls,
                         const float* __restrict__ bmu, const float* __restrict__ bls,
                         const float* __restrict__ eps,
                         float* __restrict__ mu_out, float* __restrict__ ls_out,
                         unsigned short* __restrict__ zh, unsigned short* __restrict__ zl) {
    int t = blockIdx.x * 256 + threadIdx.x;
    int i = t >> 6, l = t & 63;
    int c = l & 31;
    int beg = row[i], end = row[i + 1];
    const float* tp = (l < 32) ? tmu : tls;
    float di = dinv[i];
    float acc = di * di * tp[i * FO + c];
    for (int j = beg; j < end; ++j) {
        int s = csr_s[j];
        float w = csr_w[j];
        acc = fmaf(w, tp[s * FO + c], acc);
    }
    float v = acc + ((l < 32) ? bmu[c] : bls[c]);
    if (l < 32) mu_out[i * FO + c] = v;
    else        ls_out[i * FO + c] = v;
    float other = __shfl_xor(v, 32);   // lane<32 gets ls
    if (l < 32) {
        float zf = fmaf(eps[i * FO + c], __expf(other), v);
        unsigned short hb = f2bf(zf);
        zh[i * FO + c] = hb;
        zl[i * FO + c] = f2bf(zf - bf2f(hb));
    }
}

// ---------------- decode: adj = sigmoid(z @ z^T) ----------------
// BEST-KNOWN CONFIG (round 14, 311us): 16 rows x 1024 cols per block; wave w
// owns cols [w*256,+256) in TWO groups of 128. Slab [4][16][136] = 34.8KB ->
// 4 blocks/CU (measured optimum of 2/4/8 sweep; persistent variant was worse).
// Per-wave private slab, no barriers, bj-fast block order, non-temporal
// 512B-contiguous stores.
__global__ __launch_bounds__(256, 4) void k_decode(const unsigned short* __restrict__ zh,
                                                   const unsigned short* __restrict__ zl,
                                                   float* __restrict__ out) {
    __shared__ float slab[4][16][136];   // 34.8 KB
    int bj = blockIdx.x & 15, bi = blockIdx.x >> 4;   // bj (col panel) fast
    int w = threadIdx.x >> 6;
    int l = threadIdx.x & 63;
    int lr = l & 15, lg = l >> 4;

    auto ld = [&](const unsigned short* p, int t) -> bf16x8 {
        return *(const bf16x8*)(p + ((size_t)t * 16 + lr) * FO + lg * 8);
    };

    bf16x8 rh = ld(zh, bi), rl = ld(zl, bi);   // rows bi*16..+15

    int ctbase = bj * 64 + w * 16;
#pragma unroll
    for (int g = 0; g < 2; ++g) {
        // compute 8 col-tiles (128 cols) into the slab
#pragma unroll
        for (int j = 0; j < 8; ++j) {
            int ct = ctbase + g * 8 + j;
            bf16x8 ch = ld(zh, ct);
            bf16x8 cl = ld(zl, ct);
            f32x4 a = {0.f, 0.f, 0.f, 0.f};
            a = __builtin_amdgcn_mfma_f32_16x16x32_bf16(ch, rh, a, 0, 0, 0);
            a = __builtin_amdgcn_mfma_f32_16x16x32_bf16(ch, rl, a, 0, 0, 0);
            a = __builtin_amdgcn_mfma_f32_16x16x32_bf16(cl, rh, a, 0, 0, 0);
            float4 v;
            v.x = __builtin_amdgcn_rcpf(1.f + __expf(-a[0]));
            v.y = __builtin_amdgcn_rcpf(1.f + __expf(-a[1]));
            v.z = __builtin_amdgcn_rcpf(1.f + __expf(-a[2]));
            v.w = __builtin_amdgcn_rcpf(1.f + __expf(-a[3]));
            *(float4*)&slab[w][lr][j * 16 + lg * 4] = v;
        }
        // write out: 8 insts, each = 2 rows x 512B contiguous, non-temporal
        size_t cbase = (size_t)bj * 1024 + w * 256 + g * 128;
#pragma unroll
        for (int inst = 0; inst < 8; ++inst) {
            int r = inst * 2 + (l >> 5);
            int f4 = l & 31;
            f32x4 v = *(const f32x4*)&slab[w][r][f4 * 4];
            f32x4* dst = (f32x4*)(out + ((size_t)(bi * 16 + r)) * NN + cbase + f4 * 4);
            __builtin_nontemporal_store(v, dst);
        }
    }
}

// ---------------- launch ----------------

extern "C" void kernel_launch(void* const* d_in, const int* in_sizes, int n_in,
                              void* d_out, int out_size, void* d_ws, size_t ws_size,
                              hipStream_t stream) {
    const float* x    = (const float*)d_in[0];
    const int*   ei   = (const int*)d_in[1];
    const float* W1   = (const float*)d_in[2];
    const float* b1   = (const float*)d_in[3];
    const float* Wmu  = (const float*)d_in[4];
    const float* bmu  = (const float*)d_in[5];
    const float* Wls  = (const float*)d_in[6];
    const float* bls  = (const float*)d_in[7];
    const float* eps  = (const float*)d_in[8];

    int E = in_sizes[1] / 2;
    int nf = (E + 255) / 256;
    const int* src = ei;
    const int* dst = ei + E;

    float* ws = (float*)d_ws;
    float* dinv  = ws;                         // NN f32
    int*   cnt   = (int*)(dinv + NN);          // NN
    int*   row   = cnt + NN;                   // NN+16
    int*   cur   = row + NN + 16;              // NN
    int*   csr_s = cur + NN;                   // E
    float* csr_w = (float*)(csr_s + E);        // E
    float* h0    = csr_w + E;                  // NN*FH
    float* tmu   = h0 + (size_t)NN * FH;       // NN*FO
    float* tls   = tmu + (size_t)NN * FO;      // NN*FO
    unsigned short* zh = (unsigned short*)(tls + (size_t)NN * FO);  // NN*FO u16
    unsigned short* zl = zh + (size_t)NN * FO;                      // NN*FO u16

    float* adj    = (float*)d_out;
    float* mu_out = adj + (size_t)NN * NN;
    float* ls_out = mu_out + (size_t)NN * FO;

    k_zero<<<NN / 256, 256, 0, stream>>>(cnt);
    k_count<<<nf, 256, 0, stream>>>(dst, cnt, E);
    k_scan<<<1, 256, 0, stream>>>(cnt, row, dinv, cur);
    k_fill_h0<<<nf + NN / 4, 256, 0, stream>>>(src, dst, row, cur, dinv,
                                               csr_s, csr_w, E, nf, x, W1, h0);
    k_prop1t<<<NN * FH / 256, 256, 0, stream>>>(row, csr_s, csr_w, dinv, h0, b1,
                                                Wmu, Wls, tmu, tls);
    k_prop2g<<<NN * FH / 256, 256, 0, stream>>>(row, csr_s, csr_w, dinv, tmu, tls,
                                                bmu, bls, eps, mu_out, ls_out, zh, zl);
    k_decode<<<(NN / 16) * (NN / 1024), 256, 0, stream>>>(zh, zl, adj);
}